// Round 16
// baseline (606.147 us; speedup 1.0000x reference)
//
#include <hip/hip_runtime.h>

// SwinTransformerBlock on MI355X (gfx950).
// Pipeline (6 launches):
//   k_prep    : casts qkv_w/proj_w/x fp32->bf16, builds mbi packed table
//   k_qkv     : MFMA GEMM qkv = xb @ qkv_w^T + b (q pre-scaled), bf16 out.
//               256x128 tile, 512 thr (8 waves 4Mx2N), pure-DMA dbuf,
//               counted vmcnt(3), slot-XOR swizzle. 24 waves/CU.
//   k_bqk     : bqk[b,h,t] = q0.q_rpe + k0.k_rpe as MFMA GEMM
//   k_attn    : one WAVE per (b,h): S^T=mfma(K,Q) -> bias/mask -> softmax ->
//               PV via 2KB P-slab; V transposed+swizzled; attn via LDS-staged
//               coalesced stores (R13-proven).
//   k_rv      : per (h,i,b-chunk): MFMA, B-fragments direct from fp32 attn, RMW o1
//   k_proj    : out = o1 @ proj_w^T + proj_b, 256x128 tile, 512 thr, dbuf

typedef unsigned int u32;
typedef unsigned short u16;
typedef __attribute__((ext_vector_type(8))) short bf16x8;
typedef __attribute__((ext_vector_type(4))) float f32x4;
typedef float f4a __attribute__((ext_vector_type(4), aligned(4)));

#define SCALE 0.17677669529663687f   // 32^-0.5

__device__ __forceinline__ u16 f2b(float f) {
  union { float f; u32 u; } c; c.f = f;
  u32 u = c.u;
  return (u16)((u + 0x7FFFu + ((u >> 16) & 1u)) >> 16);   // RNE
}
__device__ __forceinline__ float b2f(u16 s) {
  union { float f; u32 u; } c; c.u = ((u32)s) << 16;
  return c.f;
}
__device__ __forceinline__ u32 pk2(float lo, float hi) {
  return (u32)f2b(lo) | ((u32)f2b(hi) << 16);
}
__device__ __forceinline__ void async16(void* lds, const void* g) {
  __builtin_amdgcn_global_load_lds(
      (const __attribute__((address_space(1))) u32*)g,
      (__attribute__((address_space(3))) u32*)lds, 16, 0, 0);
}

// prep: cast qkv_w (0..431), proj_w (432..575), mbi (576..1176), x (1177..3224)
__global__ __launch_bounds__(256) void k_prep(
    const float* __restrict__ qkv_w, const float* __restrict__ proj_w,
    const float* __restrict__ mask, const int* __restrict__ idx,
    const float* __restrict__ x,
    u16* __restrict__ wqkvb, u16* __restrict__ wprojb, u16* __restrict__ mbi,
    u16* __restrict__ xb) {
  int bx = blockIdx.x, tid = threadIdx.x;
  if (bx < 432) {
    int i = bx * 256 + tid;
    float4 v = ((const float4*)qkv_w)[i];
    ushort4 o; o.x = f2b(v.x); o.y = f2b(v.y); o.z = f2b(v.z); o.w = f2b(v.w);
    ((ushort4*)wqkvb)[i] = o;
  } else if (bx < 576) {
    int i = (bx - 432) * 256 + tid;
    float4 v = ((const float4*)proj_w)[i];
    ushort4 o; o.x = f2b(v.x); o.y = f2b(v.y); o.z = f2b(v.z); o.w = f2b(v.w);
    ((ushort4*)wprojb)[i] = o;
  } else if (bx < 1177) {
    int i = (bx - 576) * 256 + tid;
    if (i < 64 * 2401) {
      int p = i % 2401;
      mbi[i] = (u16)(idx[p] | ((mask[i] != 0.0f) ? 256 : 0));
    }
  } else {
    for (int i = (bx - 1177) * 256 + tid; i < 9633792; i += 2048 * 256) {
      float4 v = ((const float4*)x)[i];
      ushort4 o; o.x = f2b(v.x); o.y = f2b(v.y); o.z = f2b(v.z); o.w = f2b(v.w);
      ((ushort4*)xb)[i] = o;
    }
  }
}

// qkv[100352][1152](bf16) = xb(bf16) @ qkv_w^T + qkv_b; q cols scaled.
// 256x128 tile, 8 waves (4Mx2N), dbuf, counted vmcnt(3).
__global__ __launch_bounds__(512) void k_qkv(
    const u16* __restrict__ A, const u16* __restrict__ Bw,
    const float* __restrict__ bias, u16* __restrict__ outq) {
  int bx0 = blockIdx.x;
  int bx = (bx0 & 7) * 441 + (bx0 >> 3);     // XCD swizzle (3528 = 8*441)
  int mt = bx / 9, nt = bx - mt * 9;
  size_t m0 = (size_t)mt * 256;
  int n0 = nt * 128;
  int tid = threadIdx.x;                      // 0..511
  int w = tid >> 6, l = tid & 63;
  int wm = w >> 1, wn = w & 1;                // wm 0..3, wn 0..1
  int lr = l & 15, lg = l >> 4;
  int rdo = (lg ^ ((lr >> 1) & 3)) << 3;      // swizzled read slot (elems)

  __shared__ u16 At[2][8192];   // 256x32 per buffer (32 KB total)
  __shared__ u16 Bt[2][4096];   // 128x32 per buffer (16 KB total)

  f32x4 acc[4][4] = {};
  int row = tid >> 2;                                     // 0..127
  int c8 = (((tid & 3) ^ ((row >> 1) & 3)) << 3);         // pre-swizzled col
  // (row+128)>>1 & 3 == row>>1 & 3 (128/2 % 4 == 0) -> same c8 for both halves
  const u16* gA  = A + (m0 + row) * 384 + c8;
  const u16* gA2 = A + (m0 + row + 128) * 384 + c8;
  const u16* gB  = Bw + (size_t)(n0 + row) * 384 + c8;

  // prologue: tile 0 (3 loads/thread)
  async16(&At[0][tid * 8], gA);
  async16(&At[0][(512 + tid) * 8], gA2);
  async16(&Bt[0][tid * 8], gB);

#pragma unroll
  for (int t = 0; t < 12; ++t) {
    int cur = t & 1, nxt = cur ^ 1;
    int k1 = ((t < 11) ? (t + 1) : 11) * 32;   // clamp: uniform vmcnt
    async16(&At[nxt][tid * 8], gA + k1);
    async16(&At[nxt][(512 + tid) * 8], gA2 + k1);
    async16(&Bt[nxt][tid * 8], gB + k1);
    // tile t's 3 loads retired; t+1's 3 stay in flight
    asm volatile("s_waitcnt vmcnt(3)" ::: "memory");
    asm volatile("s_barrier" ::: "memory");
    bf16x8 af[4], bfr[4];
#pragma unroll
    for (int mi = 0; mi < 4; ++mi)
      af[mi] = *(const bf16x8*)&At[cur][(wm * 64 + mi * 16 + lr) * 32 + rdo];
#pragma unroll
    for (int ni = 0; ni < 4; ++ni)
      bfr[ni] = *(const bf16x8*)&Bt[cur][(wn * 64 + ni * 16 + lr) * 32 + rdo];
#pragma unroll
    for (int mi = 0; mi < 4; ++mi)
#pragma unroll
      for (int ni = 0; ni < 4; ++ni)
        acc[mi][ni] = __builtin_amdgcn_mfma_f32_16x16x32_bf16(af[mi], bfr[ni], acc[mi][ni], 0, 0, 0);
    // drain ds_reads before any wave's next-tile DMA lands in this buffer
    asm volatile("s_waitcnt lgkmcnt(0)\n\ts_barrier" ::: "memory");
  }
  asm volatile("s_waitcnt vmcnt(0)" ::: "memory");   // drain clamped dup DMAs

#pragma unroll
  for (int ni = 0; ni < 4; ++ni) {
    int cc = n0 + wn * 64 + ni * 16 + lr;
    float bv = bias[cc];
    float sc = (cc < 384) ? SCALE : 1.0f;
#pragma unroll
    for (int mi = 0; mi < 4; ++mi)
#pragma unroll
      for (int r = 0; r < 4; ++r) {
        size_t rr = m0 + wm * 64 + mi * 16 + lg * 4 + r;
        outq[rr * 1152 + cc] = f2b((acc[mi][ni][r] + bv) * sc);
      }
  }
}

// bqk[b][h][t] = sum_d q0*q_rpe + k0*k_rpe. MFMA M=64 b, N=192 t, K=64.
__global__ __launch_bounds__(256) void k_bqk(
    const u16* __restrict__ qkv, const float* __restrict__ q_rpe,
    const float* __restrict__ k_rpe, float* __restrict__ bqk) {
  int bx = blockIdx.x;
  int mtile = bx / 12, h = bx % 12;
  int b0 = mtile * 64;
  int tid = threadIdx.x;
  int w = tid >> 6, l = tid & 63;
  int lr = l & 15, g = l >> 4;

  __shared__ __align__(16) u16 At[64 * 64];
  __shared__ __align__(16) u16 Bt[192 * 64];

  {
    int m = tid >> 2;
#pragma unroll
    for (int rnd = 0; rnd < 2; ++rnd) {
      int c = (tid & 3) + rnd * 4;
      const u16* src = qkv + (size_t)(b0 + m) * 56448 + h * 32 +
                       ((c < 4) ? c * 8 : 384 + (c - 4) * 8);
      bf16x8 v = *(const bf16x8*)src;
      int byte = (m * 128 + c * 16) ^ ((m & 7) << 4);
      *(bf16x8*)((char*)At + byte) = v;
    }
  }
  if (tid < 192) {
    int t = tid;
#pragma unroll
    for (int c = 0; c < 8; ++c) {
      u16 pk[8];
#pragma unroll
      for (int e = 0; e < 8; ++e) {
        int d = (c & 3) * 8 + e;
        float v = 0.f;
        if (t < 169)
          v = (c < 4) ? q_rpe[(h * 32 + d) * 169 + t]
                      : k_rpe[(h * 32 + d) * 169 + t];
        pk[e] = f2b(v);
      }
      int byte = (t * 128 + c * 16) ^ ((t & 7) << 4);
      *(bf16x8*)((char*)Bt + byte) = *(bf16x8*)pk;
    }
  }
  __syncthreads();

  f32x4 acc[12] = {};
  bf16x8 af[2];
#pragma unroll
  for (int ks = 0; ks < 2; ++ks) {
    int row = w * 16 + lr;
    af[ks] = *(const bf16x8*)((const char*)At +
              ((row * 128 + ks * 64 + g * 16) ^ ((row & 7) << 4)));
  }
#pragma unroll
  for (int nt = 0; nt < 12; ++nt) {
#pragma unroll
    for (int ks = 0; ks < 2; ++ks) {
      int t = nt * 16 + lr;
      bf16x8 bf = *(const bf16x8*)((const char*)Bt +
                   ((t * 128 + ks * 64 + g * 16) ^ ((t & 7) << 4)));
      acc[nt] = __builtin_amdgcn_mfma_f32_16x16x32_bf16(af[ks], bf, acc[nt], 0, 0, 0);
    }
  }
#pragma unroll
  for (int nt = 0; nt < 12; ++nt) {
    int t = nt * 16 + lr;
    if (t < 169) {
#pragma unroll
      for (int r = 0; r < 4; ++r) {
        int b = b0 + w * 16 + g * 4 + r;
        bqk[((size_t)b * 12 + h) * 169 + t] = acc[nt][r];
      }
    }
  }
}

// One WAVE per (b,h); block = 4 waves = heads hg*4..hg*4+3 of window b.
__global__ __launch_bounds__(256) void k_attn(
    const u16* __restrict__ qkv, const float* __restrict__ bqkG,
    const u16* __restrict__ mbi,
    float* __restrict__ attn, u16* __restrict__ o1) {
  int blk0 = blockIdx.x;
  int blk = (blk0 & 7) * 768 + (blk0 >> 3);   // XCD swizzle (6144 = 8*768)
  int b = blk / 3, hg = blk % 3;
  int tid = threadIdx.x, w = tid >> 6, l = tid & 63;
  int h = hg * 4 + w;
  int lr = l & 15, g = l >> 4;

  __shared__ __align__(16) char LDSR[32160];
  u16* mbiL = (u16*)LDSR;                     // [2408] u16
  float* bqkL = (float*)(LDSR + 4832);        // [4][172] f32
  char* Uw = LDSR + 7584 + w * 6144;          // per-wave union (6144 B)
  char* vt = Uw;                              // V^T [32 d][64 j] u16, XOR-swz (4096 B)
  char* slab = Uw + 4096;                     // P slab [16 qi][64 j] u16 (2048 B)
  float* aw = (float*)Uw;                     // attn staging [784] f32 (overlay)

  const u16* qbase = qkv + (size_t)b * 49 * 1152 + h * 32;
  const u16* kbase = qbase + 384;
  const u16* vbase = qbase + 768;

  {
    const u16* mrow = mbi + (size_t)(b & 63) * 2401;
    for (int p = tid; p < 2401; p += 256) mbiL[p] = mrow[p];
  }
  // V -> LDS transposed+swizzled: lane l owns global row j=l (clamped).
  {
    int jr = (l < 49) ? l : 48;
    const u16* vr = vbase + (size_t)jr * 1152;
#pragma unroll
    for (int d0 = 0; d0 < 4; ++d0) {
      uint4 vv = *(const uint4*)(vr + d0 * 8);
      u16 el[8];
      *(uint4*)el = vv;
#pragma unroll
      for (int e = 0; e < 8; ++e) {
        int d = d0 * 8 + e;
        int byte = d * 128 + ((l * 2) ^ ((d & 7) << 4));
        *(u16*)(vt + byte) = el[e];
      }
    }
  }
  {
    const float* bg = bqkG + ((size_t)b * 12 + h) * 169;
#pragma unroll
    for (int t0 = 0; t0 < 192; t0 += 64) {
      int t = t0 + l;
      if (t < 169) bqkL[w * 172 + t] = bg[t];
    }
  }

  bf16x8 qf[4], kf[4];
#pragma unroll
  for (int t = 0; t < 4; ++t) {
    int qi = t * 16 + lr;
    int qir = (qi < 49) ? qi : 48;
    qf[t] = *(const bf16x8*)(qbase + (size_t)qir * 1152 + g * 8);
    kf[t] = *(const bf16x8*)(kbase + (size_t)qir * 1152 + g * 8);
  }

  // S^T[kj][qi]
  f32x4 S[4][4] = {};
#pragma unroll
  for (int mt = 0; mt < 4; ++mt)
#pragma unroll
    for (int nt = 0; nt < 4; ++nt)
      S[mt][nt] = __builtin_amdgcn_mfma_f32_16x16x32_bf16(kf[mt], qf[nt], S[mt][nt], 0, 0, 0);

  __syncthreads();   // mbiL ready; vt own-wave

  // bias + mask (padding -> -1e9)
#pragma unroll
  for (int nt = 0; nt < 4; ++nt) {
    int qi = nt * 16 + lr;
#pragma unroll
    for (int mt = 0; mt < 4; ++mt)
#pragma unroll
      for (int r = 0; r < 4; ++r) {
        int kj = mt * 16 + g * 4 + r;
        float s = S[mt][nt][r];
        if (qi < 49 && kj < 49) {
          u16 t = mbiL[qi * 49 + kj];
          s += bqkL[w * 172 + (t & 255)] - 100.f * (float)(t >> 8);
        } else {
          s = -1e9f;
        }
        S[mt][nt][r] = s;
      }
  }

  // wave-parallel softmax over kj
  float rinv[4];
#pragma unroll
  for (int nt = 0; nt < 4; ++nt) {
    float m = -1e30f;
#pragma unroll
    for (int mt = 0; mt < 4; ++mt)
#pragma unroll
      for (int r = 0; r < 4; ++r) m = fmaxf(m, S[mt][nt][r]);
    m = fmaxf(m, __shfl_xor(m, 16, 64));
    m = fmaxf(m, __shfl_xor(m, 32, 64));
    float sum = 0.f;
#pragma unroll
    for (int mt = 0; mt < 4; ++mt)
#pragma unroll
      for (int r = 0; r < 4; ++r) {
        float e = __expf(S[mt][nt][r] - m);
        S[mt][nt][r] = e;
        sum += e;
      }
    sum += __shfl_xor(sum, 16, 64);
    sum += __shfl_xor(sum, 32, 64);
    rinv[nt] = 1.f / sum;
  }

  // V^T fragments: 4x ds_read_b128 (conflict-free)
  bf16x8 va[2][2];
#pragma unroll
  for (int ks = 0; ks < 2; ++ks)
#pragma unroll
    for (int mtd = 0; mtd < 2; ++mtd) {
      int d = mtd * 16 + lr;
      int byte = d * 128 + ((ks * 64 + g * 16) ^ ((d & 7) << 4));
      va[ks][mtd] = *(const bf16x8*)(vt + byte);
    }

  // PV per nt-tile through the 2KB slab
  f32x4 O[2][4] = {};
  int swz = (lr & 7) << 4;
#pragma unroll
  for (int nt = 0; nt < 4; ++nt) {
#pragma unroll
    for (int mt = 0; mt < 4; ++mt) {
      u32 w0 = pk2(S[mt][nt][0], S[mt][nt][1]);
      u32 w1 = pk2(S[mt][nt][2], S[mt][nt][3]);
      int off = (lr * 128 + mt * 32 + g * 8) ^ swz;
      uint2 pk = {w0, w1};
      *(uint2*)(slab + off) = pk;
    }
    bf16x8 pb0 = *(const bf16x8*)(slab + ((lr * 128 + g * 16) ^ swz));
    bf16x8 pb1 = *(const bf16x8*)(slab + ((lr * 128 + 64 + g * 16) ^ swz));
#pragma unroll
    for (int mtd = 0; mtd < 2; ++mtd) {
      O[mtd][nt] = __builtin_amdgcn_mfma_f32_16x16x32_bf16(va[0][mtd], pb0, O[mtd][nt], 0, 0, 0);
      O[mtd][nt] = __builtin_amdgcn_mfma_f32_16x16x32_bf16(va[1][mtd], pb1, O[mtd][nt], 0, 0, 0);
    }
  }

  // store o1 (bf16)
  {
    u16* ob = o1 + (size_t)b * 49 * 384 + h * 32;
#pragma unroll
    for (int nti = 0; nti < 4; ++nti) {
      int i = nti * 16 + lr;
      if (i < 49) {
        float riv = rinv[nti];
#pragma unroll
        for (int mtd = 0; mtd < 2; ++mtd) {
          u32 w0 = pk2(O[mtd][nti][0] * riv, O[mtd][nti][1] * riv);
          u32 w1 = pk2(O[mtd][nti][2] * riv, O[mtd][nti][3] * riv);
          uint2 pk = {w0, w1};
          *(uint2*)&ob[(size_t)i * 384 + mtd * 16 + g * 4] = pk;
        }
      }
    }
  }

  // attn fp32: per nt-tile staged in overlay, coalesced stream-out
  asm volatile("s_waitcnt lgkmcnt(0)" ::: "memory");   // slab/vt reads done (own-wave)
  float* ao = attn + (size_t)(b * 12 + h) * 2401;
#pragma unroll
  for (int nt = 0; nt < 4; ++nt) {
    int qi = nt * 16 + lr;
    if (qi < 49) {
      float riv = rinv[nt];
#pragma unroll
      for (int mt = 0; mt < 4; ++mt)
#pragma unroll
        for (int r = 0; r < 4; ++r) {
          int kj = mt * 16 + g * 4 + r;
          if (kj < 49) aw[lr * 49 + kj] = S[mt][nt][r] * riv;
        }
    }
    asm volatile("s_waitcnt lgkmcnt(0)" ::: "memory");
    int lim = (nt < 3) ? 784 : 49;
#pragma unroll
    for (int it = 0; it < 13; ++it) {
      int p = l + it * 64;
      if (p < lim) ao[nt * 784 + p] = aw[p];
    }
    asm volatile("s_waitcnt lgkmcnt(0)" ::: "memory");
  }
}

// r_v: per (h,i,b-chunk of 256): R[bl,d] = attn[bl,:] @ wT[d,:]^T. RMW o1.
__global__ __launch_bounds__(256) void k_rv(
    const float* __restrict__ attn, const int* __restrict__ idx,
    const float* __restrict__ v_rpe, u16* __restrict__ o1) {
  int bx = blockIdx.x;
  int bc = bx & 7;
  int hi = bx >> 3;
  int i = hi % 49, h = hi / 49;
  int b0 = bc * 256;
  int tid = threadIdx.x;
  int w = tid >> 6, l = tid & 63;
  int lr = l & 15, g = l >> 4;

  __shared__ __align__(16) u16 wT[32 * 64];   // [d][j] swizzled

  if (tid < 196) {
    int j = tid >> 2, d0 = (tid & 3) * 8;
    const float* vr = v_rpe + ((size_t)h * 169 + idx[i * 49 + j]) * 32 + d0;
    float4 a = *(const float4*)vr;
    float4 bvv = *(const float4*)(vr + 4);
    float el[8] = {a.x, a.y, a.z, a.w, bvv.x, bvv.y, bvv.z, bvv.w};
#pragma unroll
    for (int e = 0; e < 8; ++e) {
      int d = d0 + e;
      int byte = (d * 128 + j * 2) ^ ((d & 7) << 4);
      *(u16*)((char*)wT + byte) = f2b(el[e]);
    }
  } else {
    int t = tid - 196;
    int j = 49 + (t >> 2), d0 = (t & 3) * 8;
#pragma unroll
    for (int e = 0; e < 8; ++e) {
      int d = d0 + e;
      int byte = (d * 128 + j * 2) ^ ((d & 7) << 4);
      *(u16*)((char*)wT + byte) = 0;
    }
  }
  __syncthreads();

  f32x4 acc[2][4] = {};
#pragma unroll
  for (int ks = 0; ks < 2; ++ks) {
    bf16x8 af[2];
#pragma unroll
    for (int mt = 0; mt < 2; ++mt) {
      int d = mt * 16 + lr;
      int byte = (d * 128 + ks * 64 + g * 16) ^ ((d & 7) << 4);
      af[mt] = *(const bf16x8*)((const char*)wT + byte);
    }
    int j0 = ks * 32 + g * 8;
#pragma unroll
    for (int nt = 0; nt < 4; ++nt) {
      int bl = w * 64 + nt * 16 + lr;
      const float* ar = attn + ((size_t)(b0 + bl) * 12 + h) * 2401 +
                        (size_t)i * 49 + j0;
      f4a v0 = *(const f4a*)ar;
      f4a v1 = *(const f4a*)(ar + 4);
      u32 wd[4];
      wd[0] = pk2(v0[0], (j0 + 1 < 49) ? v0[1] : 0.f);
      wd[1] = pk2((j0 + 2 < 49) ? v0[2] : 0.f, (j0 + 3 < 49) ? v0[3] : 0.f);
      wd[2] = pk2((j0 + 4 < 49) ? v1[0] : 0.f, (j0 + 5 < 49) ? v1[1] : 0.f);
      wd[3] = pk2((j0 + 6 < 49) ? v1[2] : 0.f, (j0 + 7 < 49) ? v1[3] : 0.f);
      bf16x8 bfr = *(bf16x8*)wd;
#pragma unroll
      for (int mt = 0; mt < 2; ++mt)
        acc[mt][nt] = __builtin_amdgcn_mfma_f32_16x16x32_bf16(af[mt], bfr, acc[mt][nt], 0, 0, 0);
    }
  }

#pragma unroll
  for (int nt = 0; nt < 4; ++nt) {
    int bl = w * 64 + nt * 16 + lr;
    u16* ob = o1 + ((size_t)(b0 + bl) * 49 + i) * 384 + h * 32;
#pragma unroll
    for (int mt = 0; mt < 2; ++mt) {
      int d = mt * 16 + g * 4;
      uint2 old = *(uint2*)&ob[d];
      uint2 nw;
      nw.x = pk2(b2f((u16)(old.x & 0xffff)) + acc[mt][nt][0],
                 b2f((u16)(old.x >> 16)) + acc[mt][nt][1]);
      nw.y = pk2(b2f((u16)(old.y & 0xffff)) + acc[mt][nt][2],
                 b2f((u16)(old.y >> 16)) + acc[mt][nt][3]);
      *(uint2*)&ob[d] = nw;
    }
  }
}

// out[100352x384] = o1(bf16) @ proj_w^T + proj_b; 256x128 tile, 8 waves, dbuf.
__global__ __launch_bounds__(512) void k_proj(
    const u16* __restrict__ A, const u16* __restrict__ Bw,
    const float* __restrict__ bias, float* __restrict__ out) {
  int bx0 = blockIdx.x;
  int bx = (bx0 & 7) * 147 + (bx0 >> 3);     // XCD swizzle (1176 = 8*147)
  int mt = bx / 3, nt = bx - mt * 3;
  size_t m0 = (size_t)mt * 256;
  int n0 = nt * 128;
  int tid = threadIdx.x;
  int w = tid >> 6, l = tid & 63;
  int wm = w >> 1, wn = w & 1;
  int lr = l & 15, lg = l >> 4;
  int rdo = (lg ^ ((lr >> 1) & 3)) << 3;

  __shared__ u16 At[2][8192];
  __shared__ u16 Bt[2][4096];

  f32x4 acc[4][4] = {};
  int row = tid >> 2;
  int c8 = (((tid & 3) ^ ((row >> 1) & 3)) << 3);
  const u16* gA  = A + (m0 + row) * 384 + c8;
  const u16* gA2 = A + (m0 + row + 128) * 384 + c8;
  const u16* gB  = Bw + (size_t)(n0 + row) * 384 + c8;

  async16(&At[0][tid * 8], gA);
  async16(&At[0][(512 + tid) * 8], gA2);
  async16(&Bt[0][tid * 8], gB);

#pragma unroll
  for (int t = 0; t < 12; ++t) {
    int cur = t & 1, nxt = cur ^ 1;
    int k1 = ((t < 11) ? (t + 1) : 11) * 32;
    async16(&At[nxt][tid * 8], gA + k1);
    async16(&At[nxt][(512 + tid) * 8], gA2 + k1);
    async16(&Bt[nxt][tid * 8], gB + k1);
    asm volatile("s_waitcnt vmcnt(3)" ::: "memory");
    asm volatile("s_barrier" ::: "memory");
    bf16x8 af[4], bfr[4];
#pragma unroll
    for (int mi = 0; mi < 4; ++mi)
      af[mi] = *(const bf16x8*)&At[cur][(wm * 64 + mi * 16 + lr) * 32 + rdo];
#pragma unroll
    for (int ni = 0; ni < 4; ++ni)
      bfr[ni] = *(const bf16x8*)&Bt[cur][(wn * 64 + ni * 16 + lr) * 32 + rdo];
#pragma unroll
    for (int mi = 0; mi < 4; ++mi)
#pragma unroll
      for (int ni = 0; ni < 4; ++ni)
        acc[mi][ni] = __builtin_amdgcn_mfma_f32_16x16x32_bf16(af[mi], bfr[ni], acc[mi][ni], 0, 0, 0);
    asm volatile("s_waitcnt lgkmcnt(0)\n\ts_barrier" ::: "memory");
  }
  asm volatile("s_waitcnt vmcnt(0)" ::: "memory");

#pragma unroll
  for (int mi = 0; mi < 4; ++mi)
#pragma unroll
    for (int ni = 0; ni < 4; ++ni)
#pragma unroll
      for (int r = 0; r < 4; ++r) {
        int rr = wm * 64 + mi * 16 + lg * 4 + r;
        int cc = wn * 64 + ni * 16 + lr;
        out[(m0 + rr) * 384 + (size_t)(n0 + cc)] = acc[mi][ni][r] + bias[n0 + cc];
      }
}

extern "C" void kernel_launch(void* const* d_in, const int* in_sizes, int n_in,
                              void* d_out, int out_size, void* d_ws, size_t ws_size,
                              hipStream_t stream) {
  const float* x      = (const float*)d_in[0];
  const float* mask   = (const float*)d_in[1];
  const int*   rpe    = (const int*)d_in[2];
  const float* qkv_w  = (const float*)d_in[3];
  const float* qkv_b  = (const float*)d_in[4];
  const float* proj_w = (const float*)d_in[5];
  const float* proj_b = (const float*)d_in[6];
  const float* q_rpe  = (const float*)d_in[7];
  const float* k_rpe  = (const float*)d_in[8];
  const float* v_rpe  = (const float*)d_in[9];

  float* out  = (float*)d_out;
  float* attn = out + (size_t)100352 * 384;   // output 2 after output 1

  char* ws = (char*)d_ws;
  u16*   qkvb   = (u16*)ws;                     // qkv bf16:   231,211,008 B
  u16*   wqkvb  = (u16*)(ws + 231211008);       // qkv_w bf16:     884,736 B
  u16*   wprojb = (u16*)(ws + 232095744);       // proj_w bf16:    294,912 B
  u16*   mbi    = (u16*)(ws + 232390656);       // mask+idx:       307,328 B
  float* bqkG   = (float*)(ws + 232697984);     // bqk fp32:    16,613,376 B
  u16*   xb     = (u16*)(ws + 249311360);       // x bf16 (dead after k_qkv)
  u16*   o1     = xb;                           // o1 reuses xb: 77,070,336 B

  k_prep<<<3225, 256, 0, stream>>>(qkv_w, proj_w, mask, rpe, x, wqkvb, wprojb, mbi, xb);
  k_qkv<<<3528, 512, 0, stream>>>(xb, wqkvb, qkv_b, qkvb);
  k_bqk<<<384, 256, 0, stream>>>(qkvb, q_rpe, k_rpe, bqkG);
  k_attn<<<6144, 256, 0, stream>>>(qkvb, bqkG, mbi, attn, o1);
  k_rv<<<4704, 256, 0, stream>>>(attn, rpe, v_rpe, o1);
  k_proj<<<1176, 512, 0, stream>>>(o1, wprojb, proj_b, out);
}

// Round 17
// 579.223 us; speedup vs baseline: 1.0465x; 1.0465x over previous
//
#include <hip/hip_runtime.h>

// SwinTransformerBlock on MI355X (gfx950).  [R13 measured-best configuration]
// Pipeline (6 launches):
//   k_prep    : casts qkv_w/proj_w/x fp32->bf16, builds mbi packed table
//   k_qkv     : MFMA GEMM qkv = xb @ qkv_w^T + b (q pre-scaled), bf16 out.
//               Pure-DMA, triple-buffered prefetch-2, vmcnt(8), swizzled.
//   k_bqk     : bqk[b,h,t] = q0.q_rpe + k0.k_rpe as MFMA GEMM
//   k_attn    : one WAVE per (b,h): S^T=mfma(K,Q) -> bias/mask -> softmax ->
//               PV via 2KB P-slab; V transposed+swizzled [32d][64j];
//               attn fp32 via LDS-staged coalesced stores.
//   k_rv      : per (h,i,b-chunk): MFMA, B-fragments direct from fp32 attn, RMW o1
//   k_proj    : out = o1 @ proj_w^T + proj_b, triple-buffered prefetch-2

typedef unsigned int u32;
typedef unsigned short u16;
typedef __attribute__((ext_vector_type(8))) short bf16x8;
typedef __attribute__((ext_vector_type(4))) float f32x4;
typedef float f4a __attribute__((ext_vector_type(4), aligned(4)));

#define SCALE 0.17677669529663687f   // 32^-0.5

__device__ __forceinline__ u16 f2b(float f) {
  union { float f; u32 u; } c; c.f = f;
  u32 u = c.u;
  return (u16)((u + 0x7FFFu + ((u >> 16) & 1u)) >> 16);   // RNE
}
__device__ __forceinline__ float b2f(u16 s) {
  union { float f; u32 u; } c; c.u = ((u32)s) << 16;
  return c.f;
}
__device__ __forceinline__ void async16(void* lds, const void* g) {
  __builtin_amdgcn_global_load_lds(
      (const __attribute__((address_space(1))) u32*)g,
      (__attribute__((address_space(3))) u32*)lds, 16, 0, 0);
}

// prep: cast qkv_w (0..431), proj_w (432..575), mbi (576..1176), x (1177..3224)
__global__ __launch_bounds__(256) void k_prep(
    const float* __restrict__ qkv_w, const float* __restrict__ proj_w,
    const float* __restrict__ mask, const int* __restrict__ idx,
    const float* __restrict__ x,
    u16* __restrict__ wqkvb, u16* __restrict__ wprojb, u16* __restrict__ mbi,
    u16* __restrict__ xb) {
  int bx = blockIdx.x, tid = threadIdx.x;
  if (bx < 432) {
    int i = bx * 256 + tid;
    float4 v = ((const float4*)qkv_w)[i];
    ushort4 o; o.x = f2b(v.x); o.y = f2b(v.y); o.z = f2b(v.z); o.w = f2b(v.w);
    ((ushort4*)wqkvb)[i] = o;
  } else if (bx < 576) {
    int i = (bx - 432) * 256 + tid;
    float4 v = ((const float4*)proj_w)[i];
    ushort4 o; o.x = f2b(v.x); o.y = f2b(v.y); o.z = f2b(v.z); o.w = f2b(v.w);
    ((ushort4*)wprojb)[i] = o;
  } else if (bx < 1177) {
    int i = (bx - 576) * 256 + tid;
    if (i < 64 * 2401) {
      int p = i % 2401;
      mbi[i] = (u16)(idx[p] | ((mask[i] != 0.0f) ? 256 : 0));
    }
  } else {
    // x cast: 9,633,792 float4s over 2048 blocks, grid-stride
    for (int i = (bx - 1177) * 256 + tid; i < 9633792; i += 2048 * 256) {
      float4 v = ((const float4*)x)[i];
      ushort4 o; o.x = f2b(v.x); o.y = f2b(v.y); o.z = f2b(v.z); o.w = f2b(v.w);
      ((ushort4*)xb)[i] = o;
    }
  }
}

// qkv[100352][1152](bf16) = xb(bf16) @ qkv_w^T + qkv_b; q cols scaled.
// Pure-DMA, triple-buffered, prefetch-2, counted vmcnt(8), swizzled tiles.
__global__ __launch_bounds__(256) void k_qkv(
    const u16* __restrict__ A, const u16* __restrict__ Bw,
    const float* __restrict__ bias, u16* __restrict__ outq) {
  int bx0 = blockIdx.x;
  int bx = (bx0 & 7) * 882 + (bx0 >> 3);     // XCD-bijective swizzle
  int mt = bx / 9, nt = bx - mt * 9;
  size_t m0 = (size_t)mt * 128;
  int n0 = nt * 128;
  int tid = threadIdx.x;
  int w = tid >> 6, l = tid & 63;
  int wm = w >> 1, wn = w & 1;
  int lr = l & 15, lg = l >> 4;
  int rdo = (lg ^ ((lr >> 1) & 3)) << 3;     // swizzled read slot (elems)

  __shared__ u16 At[3][4096];   // triple buffer (prefetch depth 2)
  __shared__ u16 Bt[3][4096];

  f32x4 acc[4][4] = {};
  int row = tid >> 2;
  int c8 = (((tid & 3) ^ ((row >> 1) & 3)) << 3);   // pre-swizzled source col
  const u16* gA  = A + (m0 + row) * 384 + c8;
  const u16* gA2 = A + (m0 + row + 64) * 384 + c8;
  const u16* gB  = Bw + (size_t)(n0 + row) * 384 + c8;
  const u16* gB2 = Bw + (size_t)(n0 + row + 64) * 384 + c8;

  // prologue: tiles 0 and 1 (8 loads in flight)
  async16(&At[0][tid * 8], gA);
  async16(&At[0][(256 + tid) * 8], gA2);
  async16(&Bt[0][tid * 8], gB);
  async16(&Bt[0][(256 + tid) * 8], gB2);
  async16(&At[1][tid * 8], gA + 32);
  async16(&At[1][(256 + tid) * 8], gA2 + 32);
  async16(&Bt[1][tid * 8], gB + 32);
  async16(&Bt[1][(256 + tid) * 8], gB2 + 32);

#pragma unroll
  for (int t = 0; t < 12; ++t) {
    int cur = t % 3, pre = (t + 2) % 3;
    int k2 = ((t + 2 < 12) ? (t + 2) : 11) * 32;   // clamp: uniform vmcnt
    async16(&At[pre][tid * 8], gA + k2);
    async16(&At[pre][(256 + tid) * 8], gA2 + k2);
    async16(&Bt[pre][tid * 8], gB + k2);
    async16(&Bt[pre][(256 + tid) * 8], gB2 + k2);
    // <=12 outstanding; wait tile t's 4 done, keep t+1/t+2's 8 in flight
    asm volatile("s_waitcnt vmcnt(8)" ::: "memory");
    asm volatile("s_barrier" ::: "memory");
    bf16x8 af[4], bfr[4];
#pragma unroll
    for (int mi = 0; mi < 4; ++mi)
      af[mi] = *(const bf16x8*)&At[cur][(wm * 64 + mi * 16 + lr) * 32 + rdo];
#pragma unroll
    for (int ni = 0; ni < 4; ++ni)
      bfr[ni] = *(const bf16x8*)&Bt[cur][(wn * 64 + ni * 16 + lr) * 32 + rdo];
#pragma unroll
    for (int mi = 0; mi < 4; ++mi)
#pragma unroll
      for (int ni = 0; ni < 4; ++ni)
        acc[mi][ni] = __builtin_amdgcn_mfma_f32_16x16x32_bf16(af[mi], bfr[ni], acc[mi][ni], 0, 0, 0);
    // drain this wave's ds_reads before any wave's next-tile DMA lands
    asm volatile("s_waitcnt lgkmcnt(0)\n\ts_barrier" ::: "memory");
  }
  // drain leftover (clamped duplicate) DMAs before LDS teardown
  asm volatile("s_waitcnt vmcnt(0)" ::: "memory");

  int lgq = l >> 4;
#pragma unroll
  for (int ni = 0; ni < 4; ++ni) {
    int cc = n0 + wn * 64 + ni * 16 + lr;
    float bv = bias[cc];
    float sc = (cc < 384) ? SCALE : 1.0f;
#pragma unroll
    for (int mi = 0; mi < 4; ++mi)
#pragma unroll
      for (int r = 0; r < 4; ++r) {
        size_t rr = m0 + wm * 64 + mi * 16 + lgq * 4 + r;
        outq[rr * 1152 + cc] = f2b((acc[mi][ni][r] + bv) * sc);
      }
  }
}

// bqk[b][h][t] = sum_d q0*q_rpe + k0*k_rpe. MFMA M=64 b, N=192 t, K=64.
__global__ __launch_bounds__(256) void k_bqk(
    const u16* __restrict__ qkv, const float* __restrict__ q_rpe,
    const float* __restrict__ k_rpe, float* __restrict__ bqk) {
  int bx = blockIdx.x;
  int mtile = bx / 12, h = bx % 12;
  int b0 = mtile * 64;
  int tid = threadIdx.x;
  int w = tid >> 6, l = tid & 63;
  int lr = l & 15, g = l >> 4;

  __shared__ __align__(16) u16 At[64 * 64];
  __shared__ __align__(16) u16 Bt[192 * 64];

  {
    int m = tid >> 2;
#pragma unroll
    for (int rnd = 0; rnd < 2; ++rnd) {
      int c = (tid & 3) + rnd * 4;
      const u16* src = qkv + (size_t)(b0 + m) * 56448 + h * 32 +
                       ((c < 4) ? c * 8 : 384 + (c - 4) * 8);
      bf16x8 v = *(const bf16x8*)src;
      int byte = (m * 128 + c * 16) ^ ((m & 7) << 4);
      *(bf16x8*)((char*)At + byte) = v;
    }
  }
  if (tid < 192) {
    int t = tid;
#pragma unroll
    for (int c = 0; c < 8; ++c) {
      u16 pk[8];
#pragma unroll
      for (int e = 0; e < 8; ++e) {
        int d = (c & 3) * 8 + e;
        float v = 0.f;
        if (t < 169)
          v = (c < 4) ? q_rpe[(h * 32 + d) * 169 + t]
                      : k_rpe[(h * 32 + d) * 169 + t];
        pk[e] = f2b(v);
      }
      int byte = (t * 128 + c * 16) ^ ((t & 7) << 4);
      *(bf16x8*)((char*)Bt + byte) = *(bf16x8*)pk;
    }
  }
  __syncthreads();

  f32x4 acc[12] = {};
  bf16x8 af[2];
#pragma unroll
  for (int ks = 0; ks < 2; ++ks) {
    int row = w * 16 + lr;
    af[ks] = *(const bf16x8*)((const char*)At +
              ((row * 128 + ks * 64 + g * 16) ^ ((row & 7) << 4)));
  }
#pragma unroll
  for (int nt = 0; nt < 12; ++nt) {
#pragma unroll
    for (int ks = 0; ks < 2; ++ks) {
      int t = nt * 16 + lr;
      bf16x8 bf = *(const bf16x8*)((const char*)Bt +
                   ((t * 128 + ks * 64 + g * 16) ^ ((t & 7) << 4)));
      acc[nt] = __builtin_amdgcn_mfma_f32_16x16x32_bf16(af[ks], bf, acc[nt], 0, 0, 0);
    }
  }
#pragma unroll
  for (int nt = 0; nt < 12; ++nt) {
    int t = nt * 16 + lr;
    if (t < 169) {
#pragma unroll
      for (int r = 0; r < 4; ++r) {
        int b = b0 + w * 16 + g * 4 + r;
        bqk[((size_t)b * 12 + h) * 169 + t] = acc[nt][r];
      }
    }
  }
}

// One WAVE per (b,h); block = 4 waves = heads hg*4..hg*4+3 of window b.
__global__ __launch_bounds__(256) void k_attn(
    const u16* __restrict__ qkv, const float* __restrict__ bqkG,
    const u16* __restrict__ mbi,
    float* __restrict__ attn, u16* __restrict__ o1) {
  int blk0 = blockIdx.x;
  int blk = (blk0 & 7) * 768 + (blk0 >> 3);   // XCD swizzle (6144 = 8*768)
  int b = blk / 3, hg = blk % 3;
  int tid = threadIdx.x, w = tid >> 6, l = tid & 63;
  int h = hg * 4 + w;
  int lr = l & 15, g = l >> 4;

  __shared__ __align__(16) char LDSR[32160];
  u16* mbiL = (u16*)LDSR;                     // [2408] u16
  float* bqkL = (float*)(LDSR + 4832);        // [4][172] f32
  char* Uw = LDSR + 7584 + w * 6144;          // per-wave union (6144 B)
  char* vt = Uw;                              // V^T [32 d][64 j] u16, XOR-swz (4096 B)
  char* slab = Uw + 4096;                     // P slab [16 qi][64 j] u16 (2048 B)
  float* aw = (float*)Uw;                     // attn staging [784] f32 (overlay)

  const u16* qbase = qkv + (size_t)b * 49 * 1152 + h * 32;
  const u16* kbase = qbase + 384;
  const u16* vbase = qbase + 768;

  {
    const u16* mrow = mbi + (size_t)(b & 63) * 2401;
    for (int p = tid; p < 2401; p += 256) mbiL[p] = mrow[p];
  }
  // V -> LDS transposed+swizzled: lane l owns global row j=l (clamped).
  {
    int jr = (l < 49) ? l : 48;
    const u16* vr = vbase + (size_t)jr * 1152;
#pragma unroll
    for (int d0 = 0; d0 < 4; ++d0) {
      uint4 vv = *(const uint4*)(vr + d0 * 8);
      u16 el[8];
      *(uint4*)el = vv;
#pragma unroll
      for (int e = 0; e < 8; ++e) {
        int d = d0 * 8 + e;
        int byte = d * 128 + ((l * 2) ^ ((d & 7) << 4));
        *(u16*)(vt + byte) = el[e];
      }
    }
  }
  {
    const float* bg = bqkG + ((size_t)b * 12 + h) * 169;
#pragma unroll
    for (int t0 = 0; t0 < 192; t0 += 64) {
      int t = t0 + l;
      if (t < 169) bqkL[w * 172 + t] = bg[t];
    }
  }

  bf16x8 qf[4], kf[4];
#pragma unroll
  for (int t = 0; t < 4; ++t) {
    int qi = t * 16 + lr;
    int qir = (qi < 49) ? qi : 48;
    qf[t] = *(const bf16x8*)(qbase + (size_t)qir * 1152 + g * 8);
    kf[t] = *(const bf16x8*)(kbase + (size_t)qir * 1152 + g * 8);
  }

  // S^T[kj][qi]
  f32x4 S[4][4] = {};
#pragma unroll
  for (int mt = 0; mt < 4; ++mt)
#pragma unroll
    for (int nt = 0; nt < 4; ++nt)
      S[mt][nt] = __builtin_amdgcn_mfma_f32_16x16x32_bf16(kf[mt], qf[nt], S[mt][nt], 0, 0, 0);

  __syncthreads();   // mbiL ready; vt own-wave

  // bias + mask (padding -> -1e9)
#pragma unroll
  for (int nt = 0; nt < 4; ++nt) {
    int qi = nt * 16 + lr;
#pragma unroll
    for (int mt = 0; mt < 4; ++mt)
#pragma unroll
      for (int r = 0; r < 4; ++r) {
        int kj = mt * 16 + g * 4 + r;
        float s = S[mt][nt][r];
        if (qi < 49 && kj < 49) {
          u16 t = mbiL[qi * 49 + kj];
          s += bqkL[w * 172 + (t & 255)] - 100.f * (float)(t >> 8);
        } else {
          s = -1e9f;
        }
        S[mt][nt][r] = s;
      }
  }

  // wave-parallel softmax over kj
  float rinv[4];
#pragma unroll
  for (int nt = 0; nt < 4; ++nt) {
    float m = -1e30f;
#pragma unroll
    for (int mt = 0; mt < 4; ++mt)
#pragma unroll
      for (int r = 0; r < 4; ++r) m = fmaxf(m, S[mt][nt][r]);
    m = fmaxf(m, __shfl_xor(m, 16, 64));
    m = fmaxf(m, __shfl_xor(m, 32, 64));
    float sum = 0.f;
#pragma unroll
    for (int mt = 0; mt < 4; ++mt)
#pragma unroll
      for (int r = 0; r < 4; ++r) {
        float e = __expf(S[mt][nt][r] - m);
        S[mt][nt][r] = e;
        sum += e;
      }
    sum += __shfl_xor(sum, 16, 64);
    sum += __shfl_xor(sum, 32, 64);
    rinv[nt] = 1.f / sum;
  }

  // V^T fragments: 4x ds_read_b128 (conflict-free)
  bf16x8 va[2][2];
#pragma unroll
  for (int ks = 0; ks < 2; ++ks)
#pragma unroll
    for (int mtd = 0; mtd < 2; ++mtd) {
      int d = mtd * 16 + lr;
      int byte = d * 128 + ((ks * 64 + g * 16) ^ ((d & 7) << 4));
      va[ks][mtd] = *(const bf16x8*)(vt + byte);
    }

  // PV per nt-tile through the 2KB slab
  f32x4 O[2][4] = {};
  int swz = (lr & 7) << 4;
#pragma unroll
  for (int nt = 0; nt < 4; ++nt) {
#pragma unroll
    for (int mt = 0; mt < 4; ++mt) {
      u32 w0 = (u32)f2b(S[mt][nt][0]) | ((u32)f2b(S[mt][nt][1]) << 16);
      u32 w1 = (u32)f2b(S[mt][nt][2]) | ((u32)f2b(S[mt][nt][3]) << 16);
      int off = (lr * 128 + mt * 32 + g * 8) ^ swz;
      uint2 pk = {w0, w1};
      *(uint2*)(slab + off) = pk;
    }
    bf16x8 pb0 = *(const bf16x8*)(slab + ((lr * 128 + g * 16) ^ swz));
    bf16x8 pb1 = *(const bf16x8*)(slab + ((lr * 128 + 64 + g * 16) ^ swz));
#pragma unroll
    for (int mtd = 0; mtd < 2; ++mtd) {
      O[mtd][nt] = __builtin_amdgcn_mfma_f32_16x16x32_bf16(va[0][mtd], pb0, O[mtd][nt], 0, 0, 0);
      O[mtd][nt] = __builtin_amdgcn_mfma_f32_16x16x32_bf16(va[1][mtd], pb1, O[mtd][nt], 0, 0, 0);
    }
  }

  // store o1 (bf16)
  {
    u16* ob = o1 + (size_t)b * 49 * 384 + h * 32;
#pragma unroll
    for (int nti = 0; nti < 4; ++nti) {
      int i = nti * 16 + lr;
      if (i < 49) {
        float riv = rinv[nti];
#pragma unroll
        for (int mtd = 0; mtd < 2; ++mtd) {
          u32 w0 = (u32)f2b(O[mtd][nti][0] * riv) | ((u32)f2b(O[mtd][nti][1] * riv) << 16);
          u32 w1 = (u32)f2b(O[mtd][nti][2] * riv) | ((u32)f2b(O[mtd][nti][3] * riv) << 16);
          uint2 pk = {w0, w1};
          *(uint2*)&ob[(size_t)i * 384 + mtd * 16 + g * 4] = pk;
        }
      }
    }
  }

  // attn fp32: per nt-tile staged in overlay, coalesced stream-out
  asm volatile("s_waitcnt lgkmcnt(0)" ::: "memory");   // slab/vt reads done (own-wave)
  float* ao = attn + (size_t)(b * 12 + h) * 2401;
#pragma unroll
  for (int nt = 0; nt < 4; ++nt) {
    int qi = nt * 16 + lr;
    if (qi < 49) {
      float riv = rinv[nt];
#pragma unroll
      for (int mt = 0; mt < 4; ++mt)
#pragma unroll
        for (int r = 0; r < 4; ++r) {
          int kj = mt * 16 + g * 4 + r;
          if (kj < 49) aw[lr * 49 + kj] = S[mt][nt][r] * riv;
        }
    }
    asm volatile("s_waitcnt lgkmcnt(0)" ::: "memory");
    int lim = (nt < 3) ? 784 : 49;
#pragma unroll
    for (int it = 0; it < 13; ++it) {
      int p = l + it * 64;
      if (p < lim) ao[nt * 784 + p] = aw[p];
    }
    asm volatile("s_waitcnt lgkmcnt(0)" ::: "memory");
  }
}

// r_v: per (h,i,b-chunk of 256): R[bl,d] = attn[bl,:] @ wT[d,:]^T. RMW o1.
__global__ __launch_bounds__(256) void k_rv(
    const float* __restrict__ attn, const int* __restrict__ idx,
    const float* __restrict__ v_rpe, u16* __restrict__ o1) {
  int bx = blockIdx.x;
  int bc = bx & 7;
  int hi = bx >> 3;
  int i = hi % 49, h = hi / 49;
  int b0 = bc * 256;
  int tid = threadIdx.x;
  int w = tid >> 6, l = tid & 63;
  int lr = l & 15, g = l >> 4;

  __shared__ __align__(16) u16 wT[32 * 64];   // [d][j] swizzled

  if (tid < 196) {
    int j = tid >> 2, d0 = (tid & 3) * 8;
    const float* vr = v_rpe + ((size_t)h * 169 + idx[i * 49 + j]) * 32 + d0;
    float4 a = *(const float4*)vr;
    float4 bvv = *(const float4*)(vr + 4);
    float el[8] = {a.x, a.y, a.z, a.w, bvv.x, bvv.y, bvv.z, bvv.w};
#pragma unroll
    for (int e = 0; e < 8; ++e) {
      int d = d0 + e;
      int byte = (d * 128 + j * 2) ^ ((d & 7) << 4);
      *(u16*)((char*)wT + byte) = f2b(el[e]);
    }
  } else {
    int t = tid - 196;
    int j = 49 + (t >> 2), d0 = (t & 3) * 8;
#pragma unroll
    for (int e = 0; e < 8; ++e) {
      int d = d0 + e;
      int byte = (d * 128 + j * 2) ^ ((d & 7) << 4);
      *(u16*)((char*)wT + byte) = 0;
    }
  }
  __syncthreads();

  f32x4 acc[2][4] = {};
#pragma unroll
  for (int ks = 0; ks < 2; ++ks) {
    bf16x8 af[2];
#pragma unroll
    for (int mt = 0; mt < 2; ++mt) {
      int d = mt * 16 + lr;
      int byte = (d * 128 + ks * 64 + g * 16) ^ ((d & 7) << 4);
      af[mt] = *(const bf16x8*)((const char*)wT + byte);
    }
    int j0 = ks * 32 + g * 8;
#pragma unroll
    for (int nt = 0; nt < 4; ++nt) {
      int bl = w * 64 + nt * 16 + lr;
      const float* ar = attn + ((size_t)(b0 + bl) * 12 + h) * 2401 +
                        (size_t)i * 49 + j0;
      f4a v0 = *(const f4a*)ar;
      f4a v1 = *(const f4a*)(ar + 4);
      u16 pk[8];
#pragma unroll
      for (int e = 0; e < 8; ++e) {
        float vv = (e < 4) ? v0[e] : v1[e - 4];
        pk[e] = (j0 + e < 49) ? f2b(vv) : (u16)0;
      }
      bf16x8 bfr = *(bf16x8*)pk;
#pragma unroll
      for (int mt = 0; mt < 2; ++mt)
        acc[mt][nt] = __builtin_amdgcn_mfma_f32_16x16x32_bf16(af[mt], bfr, acc[mt][nt], 0, 0, 0);
    }
  }

#pragma unroll
  for (int nt = 0; nt < 4; ++nt) {
    int bl = w * 64 + nt * 16 + lr;
    u16* ob = o1 + ((size_t)(b0 + bl) * 49 + i) * 384 + h * 32;
#pragma unroll
    for (int mt = 0; mt < 2; ++mt) {
      int d = mt * 16 + g * 4;
      uint2 old = *(uint2*)&ob[d];
      uint2 nw;
      nw.x = (u32)f2b(b2f((u16)(old.x & 0xffff)) + acc[mt][nt][0]) |
             ((u32)f2b(b2f((u16)(old.x >> 16)) + acc[mt][nt][1]) << 16);
      nw.y = (u32)f2b(b2f((u16)(old.y & 0xffff)) + acc[mt][nt][2]) |
             ((u32)f2b(b2f((u16)(old.y >> 16)) + acc[mt][nt][3]) << 16);
      *(uint2*)&ob[d] = nw;
    }
  }
}

// out[100352x384] = o1(bf16) @ proj_w^T + proj_b; triple-buffered prefetch-2.
__global__ __launch_bounds__(256) void k_proj(
    const u16* __restrict__ A, const u16* __restrict__ Bw,
    const float* __restrict__ bias, float* __restrict__ out) {
  int bx0 = blockIdx.x;
  int bx = (bx0 & 7) * 294 + (bx0 >> 3);     // XCD swizzle (2352 = 8*294)
  int mt = bx / 3, nt = bx - mt * 3;
  size_t m0 = (size_t)mt * 128;
  int n0 = nt * 128;
  int tid = threadIdx.x;
  int w = tid >> 6, l = tid & 63;
  int wm = w >> 1, wn = w & 1;
  int lr = l & 15, lg = l >> 4;
  int rdo = (lg ^ ((lr >> 1) & 3)) << 3;

  __shared__ u16 At[3][4096];
  __shared__ u16 Bt[3][4096];

  f32x4 acc[4][4] = {};
  int row = tid >> 2;
  int c8 = (((tid & 3) ^ ((row >> 1) & 3)) << 3);
  const u16* gA  = A + (m0 + row) * 384 + c8;
  const u16* gA2 = A + (m0 + row + 64) * 384 + c8;
  const u16* gB  = Bw + (size_t)(n0 + row) * 384 + c8;
  const u16* gB2 = Bw + (size_t)(n0 + row + 64) * 384 + c8;

  async16(&At[0][tid * 8], gA);
  async16(&At[0][(256 + tid) * 8], gA2);
  async16(&Bt[0][tid * 8], gB);
  async16(&Bt[0][(256 + tid) * 8], gB2);
  async16(&At[1][tid * 8], gA + 32);
  async16(&At[1][(256 + tid) * 8], gA2 + 32);
  async16(&Bt[1][tid * 8], gB + 32);
  async16(&Bt[1][(256 + tid) * 8], gB2 + 32);

#pragma unroll
  for (int t = 0; t < 12; ++t) {
    int cur = t % 3, pre = (t + 2) % 3;
    int k2 = ((t + 2 < 12) ? (t + 2) : 11) * 32;
    async16(&At[pre][tid * 8], gA + k2);
    async16(&At[pre][(256 + tid) * 8], gA2 + k2);
    async16(&Bt[pre][tid * 8], gB + k2);
    async16(&Bt[pre][(256 + tid) * 8], gB2 + k2);
    asm volatile("s_waitcnt vmcnt(8)" ::: "memory");
    asm volatile("s_barrier" ::: "memory");
    bf16x8 af[4], bfr[4];
#pragma unroll
    for (int mi = 0; mi < 4; ++mi)
      af[mi] = *(const bf16x8*)&At[cur][(wm * 64 + mi * 16 + lr) * 32 + rdo];
#pragma unroll
    for (int ni = 0; ni < 4; ++ni)
      bfr[ni] = *(const bf16x8*)&Bt[cur][(wn * 64 + ni * 16 + lr) * 32 + rdo];
#pragma unroll
    for (int mi = 0; mi < 4; ++mi)
#pragma unroll
      for (int ni = 0; ni < 4; ++ni)
        acc[mi][ni] = __builtin_amdgcn_mfma_f32_16x16x32_bf16(af[mi], bfr[ni], acc[mi][ni], 0, 0, 0);
    asm volatile("s_waitcnt lgkmcnt(0)\n\ts_barrier" ::: "memory");
  }
  asm volatile("s_waitcnt vmcnt(0)" ::: "memory");

  int lgq = l >> 4;
#pragma unroll
  for (int mi = 0; mi < 4; ++mi)
#pragma unroll
    for (int ni = 0; ni < 4; ++ni)
#pragma unroll
      for (int r = 0; r < 4; ++r) {
        int rr = wm * 64 + mi * 16 + lgq * 4 + r;
        int cc = wn * 64 + ni * 16 + lr;
        out[(m0 + rr) * 384 + (size_t)(n0 + cc)] = acc[mi][ni][r] + bias[n0 + cc];
      }
}

extern "C" void kernel_launch(void* const* d_in, const int* in_sizes, int n_in,
                              void* d_out, int out_size, void* d_ws, size_t ws_size,
                              hipStream_t stream) {
  const float* x      = (const float*)d_in[0];
  const float* mask   = (const float*)d_in[1];
  const int*   rpe    = (const int*)d_in[2];
  const float* qkv_w  = (const float*)d_in[3];
  const float* qkv_b  = (const float*)d_in[4];
  const float* proj_w = (const float*)d_in[5];
  const float* proj_b = (const float*)d_in[6];
  const float* q_rpe  = (const float*)d_in[7];
  const float* k_rpe  = (const float*)d_in[8];
  const float* v_rpe  = (const float*)d_in[9];

  float* out  = (float*)d_out;
  float* attn = out + (size_t)100352 * 384;   // output 2 after output 1

  char* ws = (char*)d_ws;
  u16*   qkvb   = (u16*)ws;                     // qkv bf16:   231,211,008 B
  u16*   wqkvb  = (u16*)(ws + 231211008);       // qkv_w bf16:     884,736 B
  u16*   wprojb = (u16*)(ws + 232095744);       // proj_w bf16:    294,912 B
  u16*   mbi    = (u16*)(ws + 232390656);       // mask+idx:       307,328 B
  float* bqkG   = (float*)(ws + 232697984);     // bqk fp32:    16,613,376 B
  u16*   xb     = (u16*)(ws + 249311360);       // x bf16 (dead after k_qkv)
  u16*   o1     = xb;                           // o1 reuses xb: 77,070,336 B

  k_prep<<<3225, 256, 0, stream>>>(qkv_w, proj_w, mask, rpe, x, wqkvb, wprojb, mbi, xb);
  k_qkv<<<7056, 256, 0, stream>>>(xb, wqkvb, qkv_b, qkvb);
  k_bqk<<<384, 256, 0, stream>>>(qkvb, q_rpe, k_rpe, bqkG);
  k_attn<<<6144, 256, 0, stream>>>(qkvb, bqkG, mbi, attn, o1);
  k_rv<<<4704, 256, 0, stream>>>(attn, rpe, v_rpe, o1);
  k_proj<<<2352, 256, 0, stream>>>(o1, wprojb, proj_b, out);
}